// Round 1
// baseline (3177.295 us; speedup 1.0000x reference)
//
#include <hip/hip_runtime.h>

typedef unsigned short u16;
typedef __attribute__((ext_vector_type(8))) short short8;
typedef __attribute__((ext_vector_type(4))) float f32x4;

__device__ __forceinline__ u16 f2b(float f){
    unsigned u = __builtin_bit_cast(unsigned, f);
    u += 0x7fffu + ((u >> 16) & 1u);   // RNE
    return (u16)(u >> 16);
}
__device__ __forceinline__ float b2f(u16 s){
    unsigned u = ((unsigned)s) << 16;
    return __builtin_bit_cast(float, u);
}
__device__ __forceinline__ float sigm(float x){ return 1.f/(1.f + __expf(-x)); }
__device__ __forceinline__ float tanh_(float x){
    float e = __expf(-2.f * fabsf(x));
    float t = (1.f - e)/(1.f + e);
    return x < 0.f ? -t : t;
}

// ---------------- fp32 -> bf16 conversion ----------------
__global__ __launch_bounds__(256) void cvt_bf16(const float* __restrict__ s,
                                                u16* __restrict__ d, int n4){
    int i = blockIdx.x*256 + threadIdx.x;
    if (i < n4){
        float4 v = ((const float4*)s)[i];
        ushort4 o;
        o.x = f2b(v.x); o.y = f2b(v.y); o.z = f2b(v.z); o.w = f2b(v.w);
        ((ushort4*)d)[i] = o;
    }
}

// ---- W_ih cvt with row permutation: out row (unit*4+gate) = in row (gate*128+unit) ----
__global__ __launch_bounds__(192) void cvt_wih_perm(const float* __restrict__ s,
                                                    u16* __restrict__ d){
    int r = blockIdx.x;               // 0..511 input row
    int j = threadIdx.x;              // 0..191 float4 within row
    int g = r >> 7, u = r & 127;
    int ro = u * 4 + g;
    float4 v = ((const float4*)(s + (size_t)r * 768))[j];
    ushort4 o;
    o.x = f2b(v.x); o.y = f2b(v.y); o.z = f2b(v.z); o.w = f2b(v.w);
    ((ushort4*)(d + (size_t)ro * 768))[j] = o;
}

// ---- W_hh cvt with the same row permutation, 128 cols, bf16 out ----
__global__ __launch_bounds__(256) void cvt_whh_perm(const float* __restrict__ s,
                                                    u16* __restrict__ d){
    int idx = blockIdx.x*256 + threadIdx.x;   // 0..16383
    if (idx >= 512*32) return;
    int r = idx >> 5, j = idx & 31;           // row, float4 within row
    int g = r >> 7, u = r & 127;
    int ro = u * 4 + g;
    float4 v = ((const float4*)(s + (size_t)r * 128))[j];
    ushort4 o;
    o.x = f2b(v.x); o.y = f2b(v.y); o.z = f2b(v.z); o.w = f2b(v.w);
    ((ushort4*)(d + (size_t)ro * 128))[j] = o;
}

// ---------------- embedding-gather + input projection GEMM ----------------
// pre[m, n] = sum_k E[tok[m], k] * Wt[n, k] + bias(n);  M x 1024, K=768
// Wt rows (and hence pre cols) are PERMUTED: within each 512-half, p = unit*4+gate.
__global__ __launch_bounds__(256) void gemm_embed(
    const u16* __restrict__ E, const int* __restrict__ tok,
    const u16* __restrict__ Wt, const float* __restrict__ bf_,
    const float* __restrict__ bb_, u16* __restrict__ pre)
{
    __shared__ __align__(16) u16 Asm[128*32];
    __shared__ __align__(16) u16 Bsm[128*32];
    const int m0 = blockIdx.x * 128, n0 = blockIdx.y * 128;
    const int tid = threadIdx.x;
    const int ar = tid >> 2, ch = (tid & 3) * 8;
    const u16* ap0 = E + (size_t)tok[m0 + ar] * 768 + ch;
    const u16* ap1 = E + (size_t)tok[m0 + 64 + ar] * 768 + ch;
    const u16* bp0 = Wt + (size_t)(n0 + ar) * 768 + ch;
    const u16* bp1 = Wt + (size_t)(n0 + 64 + ar) * 768 + ch;
    const int lane = tid & 63, wave = tid >> 6;
    const int wm = (wave >> 1) * 64, wn = (wave & 1) * 64;
    const int qr = lane >> 4, lr = lane & 15;
    f32x4 acc[4][4] = {};
    for (int k0 = 0; k0 < 768; k0 += 32){
        __syncthreads();
        *(short8*)&Asm[ar*32 + ch]      = *(const short8*)(ap0 + k0);
        *(short8*)&Asm[(64+ar)*32 + ch] = *(const short8*)(ap1 + k0);
        *(short8*)&Bsm[ar*32 + ch]      = *(const short8*)(bp0 + k0);
        *(short8*)&Bsm[(64+ar)*32 + ch] = *(const short8*)(bp1 + k0);
        __syncthreads();
        short8 af[4], bfr[4];
        #pragma unroll
        for (int i = 0; i < 4; ++i){
            af[i]  = *(const short8*)&Asm[(wm + i*16 + lr)*32 + qr*8];
            bfr[i] = *(const short8*)&Bsm[(wn + i*16 + lr)*32 + qr*8];
        }
        #pragma unroll
        for (int i = 0; i < 4; ++i)
            #pragma unroll
            for (int j = 0; j < 4; ++j)
                acc[i][j] = __builtin_amdgcn_mfma_f32_16x16x32_bf16(af[i], bfr[j], acc[i][j], 0, 0, 0);
    }
    #pragma unroll
    for (int j = 0; j < 4; ++j){
        int col = n0 + wn + j*16 + lr;
        int d = col >> 9, p = col & 511;
        int uu = p >> 2, gg = p & 3;
        float bias = (d ? bb_ : bf_)[gg*128 + uu];
        #pragma unroll
        for (int i = 0; i < 4; ++i){
            #pragma unroll
            for (int r = 0; r < 4; ++r){
                int row = m0 + wm + i*16 + qr*4 + r;
                pre[(size_t)row*1024 + col] = f2b(acc[i][j][r] + bias);
            }
        }
    }
}

// ---------------- batched MFMA LSTM recurrence ----------------
// One block per (direction, group of 16 chains). 512 threads = 8 waves.
// Per step: C[512 gate-rows x 16 batches] = W_hh_perm[512x128] @ h[16x128]^T  (MFMA),
// acc initialized from precomputed pre (bias included).
// Wave w owns M rows [w*64, w*64+64). Lane layout (16x16x32 C):
//   row = (lane>>4)*4 + reg, col = lane&15  ->  with permuted rows (p = unit*4+gate),
//   each lane's f32x4 acc holds gates (i,f,g,o) of unit u = w*16 + i*4 + qr for batch lr.
// Cell state c stays in registers all T steps; h goes through swizzled LDS (bf16).
__global__ __launch_bounds__(512, 2) void lstm_rec(
    const u16* __restrict__ preW, const u16* __restrict__ preS,
    const u16* __restrict__ Whp,     // [4][512][128] bf16: wordF, wordB, sentF, sentB
    float* __restrict__ fo, float* __restrict__ fs,
    u16* __restrict__ foB, u16* __restrict__ fsB)
{
    const int bg = blockIdx.x;
    const u16* pre; const u16* wh; float* out; u16* outB;
    int T, dir, grp;
    if (bg < 4){                      // word: 2 groups x 2 dirs, T=1024
        dir = bg & 1; grp = bg >> 1;
        T = 1024; pre = preW; wh = Whp + (size_t)dir*512*128;
        out = fo; outB = foB;
    } else {                          // sent: 32 groups x 2 dirs, T=64
        int s = bg - 4; dir = s & 1; grp = s >> 1;
        T = 64; pre = preS; wh = Whp + (size_t)(2+dir)*512*128;
        out = fs; outB = fsB;
    }
    const int tid  = threadIdx.x;
    const int wave = tid >> 6, lane = tid & 63;
    const int lr = lane & 15, qr = lane >> 4;

    // chain handled by this lane's MFMA column
    const long rowBase = (long)(grp*16 + lr) * T;   // row stride == T for both cases
    const int t0 = dir ? (T-1) : 0;
    const int dt = dir ? -1 : 1;

    // A-fragments: W_hh rows for this wave, resident in VGPRs for all T steps
    short8 aw[4][4];
    #pragma unroll
    for (int i = 0; i < 4; ++i)
        #pragma unroll
        for (int kk = 0; kk < 4; ++kk)
            aw[i][kk] = *(const short8*)(wh + (size_t)(wave*64 + i*16 + lr)*128 + kk*32 + qr*8);

    // per-step pointers (advance by +-1 row each step)
    const u16* pp[4]; float* po[4]; u16* pb[4];
    #pragma unroll
    for (int i = 0; i < 4; ++i){
        int u = wave*16 + i*4 + qr;
        pp[i] = pre  + (rowBase + t0)*1024 + dir*512 + u*4;
        po[i] = out  + (rowBase + t0)*256  + dir*128 + u;
        pb[i] = outB + (rowBase + t0)*256  + dir*128 + u;
    }
    const long pstep = (long)dt * 1024;
    const long ostep = (long)dt * 256;

    // double-buffered h, bf16, XOR-swizzled to kill the 16-way bank conflict
    __shared__ __align__(16) u16 hb[2][16*128];
    for (int k = tid; k < 16*128; k += 512) hb[0][k] = 0;

    float cst[4] = {0.f, 0.f, 0.f, 0.f};
    ushort4 pc[4];
    #pragma unroll
    for (int i = 0; i < 4; ++i) pc[i] = *(const ushort4*)pp[i];
    __syncthreads();

    int cur = 0;
    for (int t = 0; t < T; ++t){
        // prefetch next step's pre (last iter reads in-workspace garbage, unused)
        ushort4 pn[4];
        #pragma unroll
        for (int i = 0; i < 4; ++i){ pp[i] += pstep; pn[i] = *(const ushort4*)pp[i]; }

        // B-fragments: h rows (batch = lr), swizzled
        short8 bfr[4];
        #pragma unroll
        for (int kk = 0; kk < 4; ++kk){
            int col = (kk*32 + qr*8) ^ ((lr & 7) << 3);
            bfr[kk] = *(const short8*)&hb[cur][lr*128 + col];
        }

        #pragma unroll
        for (int i = 0; i < 4; ++i){
            f32x4 acc;
            acc[0] = b2f(pc[i].x); acc[1] = b2f(pc[i].y);
            acc[2] = b2f(pc[i].z); acc[3] = b2f(pc[i].w);
            #pragma unroll
            for (int kk = 0; kk < 4; ++kk)
                acc = __builtin_amdgcn_mfma_f32_16x16x32_bf16(aw[i][kk], bfr[kk], acc, 0, 0, 0);
            float gi = sigm(acc[0]), gf = sigm(acc[1]);
            float gg = tanh_(acc[2]), go = sigm(acc[3]);
            float c = gf*cst[i] + gi*gg;
            cst[i] = c;
            float h = go * tanh_(c);
            *po[i] = h;              po[i] += ostep;
            u16 hv = f2b(h);
            *pb[i] = hv;             pb[i] += ostep;
            int u = wave*16 + i*4 + qr;
            hb[cur^1][lr*128 + (u ^ ((lr & 7) << 3))] = hv;
        }
        __syncthreads();
        cur ^= 1;
        #pragma unroll
        for (int i = 0; i < 4; ++i) pc[i] = pn[i];
    }
}

// ---------------- gate GEMM + blend epilogue ----------------
// gamma = sigmoid([fo|fs] @ gW^T + gb); out = gamma*fo + (1-gamma)*fs
__global__ __launch_bounds__(256) void gemm_gate(
    const u16* __restrict__ foB, const u16* __restrict__ fsB,
    const u16* __restrict__ gW, const float* __restrict__ gb,
    const float* __restrict__ fo, const float* __restrict__ fs,
    float* __restrict__ out)
{
    __shared__ __align__(16) u16 Asm[128*32];
    __shared__ __align__(16) u16 Bsm[128*32];
    const int m0 = blockIdx.x * 128, n0 = blockIdx.y * 128;
    const int tid = threadIdx.x;
    const int ar = tid >> 2, ch = (tid & 3) * 8;
    const u16* af0 = foB + (size_t)(m0 + ar) * 256 + ch;
    const u16* af1 = foB + (size_t)(m0 + 64 + ar) * 256 + ch;
    const u16* as0 = fsB + (size_t)(m0 + ar) * 256 + ch;
    const u16* as1 = fsB + (size_t)(m0 + 64 + ar) * 256 + ch;
    const u16* bp0 = gW + (size_t)(n0 + ar) * 512 + ch;
    const u16* bp1 = gW + (size_t)(n0 + 64 + ar) * 512 + ch;
    const int lane = tid & 63, wave = tid >> 6;
    const int wm = (wave >> 1) * 64, wn = (wave & 1) * 64;
    const int qr = lane >> 4, lr = lane & 15;
    f32x4 acc[4][4] = {};
    for (int k0 = 0; k0 < 512; k0 += 32){
        __syncthreads();
        const u16* s0 = (k0 < 256) ? (af0 + k0) : (as0 + (k0 - 256));
        const u16* s1 = (k0 < 256) ? (af1 + k0) : (as1 + (k0 - 256));
        *(short8*)&Asm[ar*32 + ch]      = *(const short8*)s0;
        *(short8*)&Asm[(64+ar)*32 + ch] = *(const short8*)s1;
        *(short8*)&Bsm[ar*32 + ch]      = *(const short8*)(bp0 + k0);
        *(short8*)&Bsm[(64+ar)*32 + ch] = *(const short8*)(bp1 + k0);
        __syncthreads();
        short8 af[4], bfr[4];
        #pragma unroll
        for (int i = 0; i < 4; ++i){
            af[i]  = *(const short8*)&Asm[(wm + i*16 + lr)*32 + qr*8];
            bfr[i] = *(const short8*)&Bsm[(wn + i*16 + lr)*32 + qr*8];
        }
        #pragma unroll
        for (int i = 0; i < 4; ++i)
            #pragma unroll
            for (int j = 0; j < 4; ++j)
                acc[i][j] = __builtin_amdgcn_mfma_f32_16x16x32_bf16(af[i], bfr[j], acc[i][j], 0, 0, 0);
    }
    #pragma unroll
    for (int j = 0; j < 4; ++j){
        int col = n0 + wn + j*16 + lr;   // 0..255
        float bias = gb[col];
        #pragma unroll
        for (int i = 0; i < 4; ++i){
            #pragma unroll
            for (int r = 0; r < 4; ++r){
                int row = m0 + wm + i*16 + qr*4 + r;
                size_t o = (size_t)row*256 + col;
                float gamma = sigm(acc[i][j][r] + bias);
                out[o] = gamma * fo[o] + (1.f - gamma) * fs[o];
            }
        }
    }
}

extern "C" void kernel_launch(void* const* d_in, const int* in_sizes, int n_in,
                              void* d_out, int out_size, void* d_ws, size_t ws_size,
                              hipStream_t stream)
{
    (void)in_sizes; (void)n_in; (void)out_size; (void)ws_size;
    const int*   wordTok = (const int*)d_in[0];
    const int*   sentTok = (const int*)d_in[1];
    const float* E       = (const float*)d_in[3];
    const float* WihWf   = (const float*)d_in[4];
    const float* WhhWf   = (const float*)d_in[5];
    const float* bWf     = (const float*)d_in[6];
    const float* WihWb   = (const float*)d_in[7];
    const float* WhhWb   = (const float*)d_in[8];
    const float* bWb     = (const float*)d_in[9];
    const float* WihSf   = (const float*)d_in[10];
    const float* WhhSf   = (const float*)d_in[11];
    const float* bSf     = (const float*)d_in[12];
    const float* WihSb   = (const float*)d_in[13];
    const float* WhhSb   = (const float*)d_in[14];
    const float* bSb     = (const float*)d_in[15];
    const float* gateW   = (const float*)d_in[16];
    const float* gateB   = (const float*)d_in[17];
    float* out = (float*)d_out;

    char* w = (char*)d_ws;
    u16* Eb   = (u16*)w;  w += (size_t)30522*768*2;
    u16* Ww   = (u16*)w;  w += (size_t)1024*768*2;
    u16* Ws_  = (u16*)w;  w += (size_t)1024*768*2;
    u16* gWb  = (u16*)w;  w += (size_t)256*512*2;
    u16* preW = (u16*)w;  w += (size_t)32768*1024*2;
    u16* preS = (u16*)w;  w += (size_t)32768*1024*2;
    float* fo = (float*)w; w += (size_t)32768*256*4;
    float* fs = (float*)w; w += (size_t)32768*256*4;
    u16* foB  = (u16*)w;  w += (size_t)32768*256*2;
    u16* fsB  = (u16*)w;  w += (size_t)32768*256*2;
    u16* Whp  = (u16*)w;  w += (size_t)4*512*128*2;

    const int nE4 = 30522*768/4;
    cvt_bf16<<<(nE4+255)/256, 256, 0, stream>>>(E, Eb, nE4);
    cvt_wih_perm<<<512, 192, 0, stream>>>(WihWf, Ww);
    cvt_wih_perm<<<512, 192, 0, stream>>>(WihWb, Ww + 512*768);
    cvt_wih_perm<<<512, 192, 0, stream>>>(WihSf, Ws_);
    cvt_wih_perm<<<512, 192, 0, stream>>>(WihSb, Ws_ + 512*768);
    const int nG4 = 256*512/4;
    cvt_bf16<<<(nG4+255)/256, 256, 0, stream>>>(gateW, gWb, nG4);
    cvt_whh_perm<<<64, 256, 0, stream>>>(WhhWf, Whp);
    cvt_whh_perm<<<64, 256, 0, stream>>>(WhhWb, Whp + 512*128);
    cvt_whh_perm<<<64, 256, 0, stream>>>(WhhSf, Whp + 2*512*128);
    cvt_whh_perm<<<64, 256, 0, stream>>>(WhhSb, Whp + 3*512*128);

    gemm_embed<<<dim3(256,8), 256, 0, stream>>>(Eb, wordTok, Ww, bWf, bWb, preW);
    gemm_embed<<<dim3(256,8), 256, 0, stream>>>(Eb, sentTok, Ws_, bSf, bSb, preS);
    lstm_rec<<<68, 512, 0, stream>>>(preW, preS, Whp, fo, fs, foB, fsB);
    gemm_gate<<<dim3(256,2), 256, 0, stream>>>(foB, fsB, gWb, gateB, fo, fs, out);
}